// Round 11
// baseline (210.651 us; speedup 1.0000x reference)
//
#include <hip/hip_runtime.h>
#include <math.h>

#define DIM_    128
#define QH_     16
#define KVH_    4
#define WIN_    512
#define BATCH_  4
#define SEQ_    2048
#define QKV_LD  3072
#define ATT_LD  2048

#define NX   (BATCH_*SEQ_*DIM_)   // 1048576
#define NWQ  (DIM_*QKV_LD)        // 393216
#define NWP  (ATT_LD*DIM_)        // 262144

typedef __attribute__((ext_vector_type(8))) short short8;
typedef __attribute__((ext_vector_type(4))) float f32x4;
typedef unsigned short u16;
typedef unsigned int u32;

__device__ __forceinline__ u16 f2bf(float f) {
    u32 u = __float_as_uint(f);
    u += 0x7fff + ((u >> 16) & 1);
    return (u16)(u >> 16);
}
__device__ __forceinline__ float bf2f(u16 u) {
    return __uint_as_float(((u32)u) << 16);
}
#define MFMA16 __builtin_amdgcn_mfma_f32_16x16x32_bf16

#if __has_builtin(__builtin_amdgcn_exp2f)
#define EXP2F __builtin_amdgcn_exp2f
#else
#define EXP2F exp2f
#endif

__device__ __forceinline__ void gload_lds16(const u16* g, u16* l) {
    __builtin_amdgcn_global_load_lds(
        (const __attribute__((address_space(1))) unsigned int*)(const void*)g,
        (__attribute__((address_space(3))) unsigned int*)(void*)l, 16, 0, 0);
}

// ---------- prep: xcvt + wtrans fused (one launch) -------------------------
// blocks [0,1024): x -> bf16 vectorized. blocks [1024,1664): W transposes
// via 32x32 LDS tiles.
__global__ __launch_bounds__(256) void prep(
    const float* __restrict__ x, const float* __restrict__ Wqkv,
    const float* __restrict__ Wproj,
    u16* __restrict__ xh, u16* __restrict__ wth, u16* __restrict__ wpth)
{
    if (blockIdx.x < 1024) {
        const size_t t = (size_t)blockIdx.x * 256 + threadIdx.x;
        float4 v = *(const float4*)(x + 4 * t);
        ushort4 o;
        o.x = f2bf(v.x); o.y = f2bf(v.y); o.z = f2bf(v.z); o.w = f2bf(v.w);
        *(ushort4*)(xh + 4 * t) = o;
        return;
    }
    __shared__ float T[32][33];
    int tile = blockIdx.x - 1024;
    const float* src; u16* dst; int K, N;
    if (tile < 384) { src = Wqkv;  dst = wth;  K = 128;  N = 3072; }
    else { tile -= 384; src = Wproj; dst = wpth; K = 2048; N = 128; }
    const int ntile = N >> 5;
    const int k0 = (tile / ntile) << 5, n0 = (tile % ntile) << 5;
    const int tx = threadIdx.x & 31, ty = threadIdx.x >> 5;
    #pragma unroll
    for (int i = 0; i < 4; ++i)
        T[ty + 8 * i][tx] = src[(size_t)(k0 + ty + 8 * i) * N + n0 + tx];
    __syncthreads();
    #pragma unroll
    for (int i = 0; i < 4; ++i)
        dst[(size_t)(n0 + ty + 8 * i) * K + k0 + tx] = f2bf(T[tx][ty + 8 * i]);
}

// ---------- GEMM1 (bf16 MFMA, LDS-tiled): qkv = x @ Wqkv (unchanged) -------
__global__ __launch_bounds__(256) void gemm1_mfma(
    const u16* __restrict__ xh, const u16* __restrict__ wth,
    u16* __restrict__ qkvb, u16* __restrict__ vg)
{
    __shared__ u16 Ab[32][512];
    __shared__ u16 Bb[16][512];
    const int bn = blockIdx.x * 64;
    const int bm = blockIdx.y * 128;
    const int tid = threadIdx.x;
    const int wv = tid >> 6, lane = tid & 63;
    const int lr = lane & 15, quad = lane >> 4;
    const int lo = lane & 15, hi = lane >> 4;

    #pragma unroll
    for (int i = 0; i < 12; ++i) {
        const int idx = wv * 12 + i;
        if (idx < 32) {
            const int mt = idx >> 2, s = idx & 3;
            gload_lds16(xh + (size_t)(bm + mt * 16 + lo) * DIM_ + s * 32 + hi * 8,
                        &Ab[idx][0]);
        } else {
            const int j = idx - 32, nt = j >> 2, s = j & 3;
            gload_lds16(wth + (size_t)(bn + nt * 16 + lo) * DIM_ + s * 32 + hi * 8,
                        &Bb[j][0]);
        }
    }
    __syncthreads();

    const int wr = wv >> 1, wc = wv & 1;
    f32x4 acc[4][2] = {};
    if (bn < 2560) {                       // transposed: ushort4 stores
        #pragma unroll
        for (int s = 0; s < 4; ++s) {
            short8 af[4], bf[2];
            #pragma unroll
            for (int mt = 0; mt < 4; ++mt)
                af[mt] = *(const short8*)&Ab[(wr * 4 + mt) * 4 + s][lane * 8];
            #pragma unroll
            for (int nt = 0; nt < 2; ++nt)
                bf[nt] = *(const short8*)&Bb[(wc * 2 + nt) * 4 + s][lane * 8];
            #pragma unroll
            for (int mt = 0; mt < 4; ++mt)
                #pragma unroll
                for (int nt = 0; nt < 2; ++nt)
                    acc[mt][nt] = MFMA16(bf[nt], af[mt], acc[mt][nt], 0, 0, 0);
        }
        #pragma unroll
        for (int mt = 0; mt < 4; ++mt)
            #pragma unroll
            for (int nt = 0; nt < 2; ++nt) {
                ushort4 o;
                o.x = f2bf(acc[mt][nt][0]); o.y = f2bf(acc[mt][nt][1]);
                o.z = f2bf(acc[mt][nt][2]); o.w = f2bf(acc[mt][nt][3]);
                *(ushort4*)(qkvb
                    + (size_t)(bm + wr * 64 + mt * 16 + lr) * QKV_LD
                    + bn + wc * 32 + nt * 16 + quad * 4) = o;
            }
    } else {                               // V region: normal, seq in regs
        #pragma unroll
        for (int s = 0; s < 4; ++s) {
            short8 af[4], bf[2];
            #pragma unroll
            for (int mt = 0; mt < 4; ++mt)
                af[mt] = *(const short8*)&Ab[(wr * 4 + mt) * 4 + s][lane * 8];
            #pragma unroll
            for (int nt = 0; nt < 2; ++nt)
                bf[nt] = *(const short8*)&Bb[(wc * 2 + nt) * 4 + s][lane * 8];
            #pragma unroll
            for (int mt = 0; mt < 4; ++mt)
                #pragma unroll
                for (int nt = 0; nt < 2; ++nt)
                    acc[mt][nt] = MFMA16(af[mt], bf[nt], acc[mt][nt], 0, 0, 0);
        }
        #pragma unroll
        for (int mt = 0; mt < 4; ++mt)
            #pragma unroll
            for (int nt = 0; nt < 2; ++nt) {
                const int ncol = bn + wc * 32 + nt * 16 + lr - 2560;
                const int kvh = ncol >> 7, d = ncol & 127;
                const int m0 = bm + wr * 64 + mt * 16 + quad * 4;
                ushort4 o;
                o.x = f2bf(acc[mt][nt][0]); o.y = f2bf(acc[mt][nt][1]);
                o.z = f2bf(acc[mt][nt][2]); o.w = f2bf(acc[mt][nt][3]);
                *(ushort4*)(vg + ((size_t)((m0 >> 11) * KVH_ + kvh) * DIM_ + d)
                            * SEQ_ + (m0 & 2047)) = o;
            }
    }
}

// ---------- Attention: R8 pipeline, 49KB LDS (3 blocks/CU) -----------------
// Same 32-key chunks / 1 barrier per chunk / same compute as R8. Changes:
// (1) staging moved POST-barrier: at that point every wave has passed
//     barrier(ch), so writing K slot (ch+2)%3 and V slot (ch+1)&1 cannot
//     collide with any reader (readers use ch%3 / ch&1) -> K ring 3, V ring 2.
// (2) uniform s_waitcnt vmcnt(2) pre-barrier: drains K(ch),V(ch) exactly,
//     keeps K(ch+2)'s 2 loads in flight (K 2-iter lead, V 1-iter lead).
__global__ __launch_bounds__(256) void attn_mfma(
    const u16* __restrict__ qkvb, const u16* __restrict__ vg,
    u16* __restrict__ ah)
{
    const int qt = blockIdx.x, kvh = blockIdx.y, b = blockIdx.z;
    const int q0 = qt << 5;
    const int tid = threadIdx.x;
    const int wv = tid >> 6, lane = tid & 63;
    const int lr = lane & 15, quad = lane >> 4;
    const int h = kvh * 4 + wv;

    __shared__ u16 Kb[3][8][512];    // 24KB  3-slot ring, sub p = nt*4+s
    __shared__ u16 Vb[2][8][512];    // 16KB  2-slot ring
    __shared__ u16 Pt[4][32][36];    // 9KB   per-wave P^T [query][key]

    const float scale2 = 0.08838834764831845f * 1.4426950408889634f;
    const float slope2 = exp2f(-0.5f * (float)(h + 1)) * 1.4426950408889634f;
    const int jbase = max(0, q0 - WIN_);
    const int nch = (q0 + 32 - jbase) >> 5;
    const size_t rowb = (size_t)b * SEQ_;
    const u16* kg  = qkvb + rowb * QKV_LD + (QH_ + kvh) * DIM_;
    const u16* vgb = vg + (size_t)(b * KVH_ + kvh) * DIM_ * SEQ_;
    const int lo = lane & 15, hi = lane >> 4;

    short8 qf[2][4];
    #pragma unroll
    for (int m = 0; m < 2; ++m) {
        const u16* qp = qkvb + (rowb + q0 + m * 16 + lr) * QKV_LD
                        + h * DIM_ + quad * 8;
        #pragma unroll
        for (int s = 0; s < 4; ++s) qf[m][s] = *(const short8*)(qp + 32 * s);
    }

    float alpha[2];
    #pragma unroll
    for (int m = 0; m < 2; ++m) {
        const int q = q0 + m * 16 + lr;
        const int rm = (q < WIN_) ? q : WIN_;
        alpha[m] = slope2 * (float)(q - rm);
    }

    f32x4 O[2][8] = {};              // O^T: regs = d, lane col = query
    float rs[2] = {0.f, 0.f};

    // per wave: K chunk = 2 loads (subs wv, wv+4), V chunk = 2 loads
    #define STAGE_K(CH, SLOT) do {                                            \
        const int _jk = jbase + ((CH) << 5);                                  \
        _Pragma("unroll")                                                     \
        for (int _t = 0; _t < 2; ++_t) {                                      \
            const int _p = wv + _t * 4;                                       \
            gload_lds16(kg + (size_t)(_jk + (_p >> 2) * 16 + lo) * QKV_LD     \
                        + (_p & 3) * 32 + hi * 8, &Kb[(SLOT)][_p][0]);        \
        }                                                                     \
    } while (0)
    #define STAGE_V(CH, SLOT) do {                                            \
        const int _jv = jbase + ((CH) << 5);                                  \
        _Pragma("unroll")                                                     \
        for (int _t = 0; _t < 2; ++_t) {                                      \
            const int _p = wv + _t * 4;                                       \
            gload_lds16(vgb + (size_t)(_p * 16 + lo) * SEQ_ + _jv + hi * 8,   \
                        &Vb[(SLOT)][_p][0]);                                  \
        }                                                                     \
    } while (0)

    // warm-up queue: K0(2), V0(2), K1(2)
    STAGE_K(0, 0);
    STAGE_V(0, 0);
    { const int c1 = (1 < nch) ? 1 : 0; STAGE_K(c1, 1); }

    for (int ch = 0; ch < nch; ++ch) {
        const int jk = jbase + (ch << 5);
        const int ks = ch % 3, vs = ch & 1;
        // drain K(ch)+V(ch); keep K(ch+1)'s 2 loads in flight
        __asm__ volatile("s_waitcnt vmcnt(2)" ::: "memory");
        __asm__ volatile("s_barrier" ::: "memory");
        // post-barrier staging into provably-dead slots (clamped at range end)
        { const int vc = (ch + 1 < nch) ? ch + 1 : nch - 1;
          STAGE_V(vc, (ch + 1) & 1); }
        { const int kc = (ch + 2 < nch) ? ch + 2 : nch - 1;
          STAGE_K(kc, (ch + 2) % 3); }

        #pragma unroll
        for (int nt = 0; nt < 2; ++nt) {
            f32x4 c0 = {0.f, 0.f, 0.f, 0.f}, c1 = {0.f, 0.f, 0.f, 0.f};
            #pragma unroll
            for (int s = 0; s < 4; ++s) {
                short8 kf = *(const short8*)&Kb[ks][nt * 4 + s][lane * 8];
                c0 = MFMA16(kf, qf[0][s], c0, 0, 0, 0);
                c1 = MFMA16(kf, qf[1][s], c1, 0, 0, 0);
            }
            const int jknt = jk + nt * 16;
            #pragma unroll
            for (int m = 0; m < 2; ++m) {
                const f32x4 c = m ? c1 : c0;
                const int qm0 = q0 + m * 16;
                const float b0 = fmaf(-slope2, (float)(jknt + quad * 4), alpha[m]);
                float e0, e1, e2, e3;
                if (qm0 >= jknt + 15 && qm0 + 15 <= jknt + WIN_) {   // full
                    e0 = EXP2F(fmaf(c[0], scale2, b0));
                    e1 = EXP2F(fmaf(c[1], scale2, b0 - slope2));
                    e2 = EXP2F(fmaf(c[2], scale2, b0 - 2.f * slope2));
                    e3 = EXP2F(fmaf(c[3], scale2, b0 - 3.f * slope2));
                } else {                                              // edge
                    const int q = qm0 + lr, j0q = jknt + quad * 4;
                    float ee[4];
                    #pragma unroll
                    for (int r = 0; r < 4; ++r) {
                        const int rel = q - (j0q + r);
                        const float t = fmaf(c[r], scale2, b0 - (float)r * slope2);
                        ee[r] = ((unsigned)rel <= (unsigned)WIN_) ? EXP2F(t) : 0.f;
                    }
                    e0 = ee[0]; e1 = ee[1]; e2 = ee[2]; e3 = ee[3];
                }
                rs[m] += (e0 + e1) + (e2 + e3);
                ushort4 o;
                o.x = f2bf(e0); o.y = f2bf(e1); o.z = f2bf(e2); o.w = f2bf(e3);
                *(ushort4*)&Pt[wv][m * 16 + lr][nt * 16 + quad * 4] = o;
            }
        }
        __asm__ volatile("s_waitcnt lgkmcnt(0)" ::: "memory");

        short8 pa0 = *(const short8*)&Pt[wv][lr][quad * 8];
        short8 pa1 = *(const short8*)&Pt[wv][16 + lr][quad * 8];
        #pragma unroll
        for (int nt = 0; nt < 8; ++nt) {
            short8 vf = *(const short8*)&Vb[vs][nt][lane * 8];
            O[0][nt] = MFMA16(vf, pa0, O[0][nt], 0, 0, 0);
            O[1][nt] = MFMA16(vf, pa1, O[1][nt], 0, 0, 0);
        }
    }
    #undef STAGE_K
    #undef STAGE_V

    // drain outstanding LDS-DMA before endpgm (LDS deallocated at exit)
    __asm__ volatile("s_waitcnt vmcnt(0)" ::: "memory");

    #pragma unroll
    for (int m = 0; m < 2; ++m) {
        rs[m] += __shfl_xor(rs[m], 16);
        rs[m] += __shfl_xor(rs[m], 32);
    }

    #pragma unroll
    for (int m = 0; m < 2; ++m) {
        const float inv = 1.0f / rs[m];
        u16* dst = ah + (rowb + q0 + m * 16 + lr) * (size_t)ATT_LD + h * DIM_;
        #pragma unroll
        for (int nt = 0; nt < 8; ++nt) {
            ushort4 o;
            o.x = f2bf(O[m][nt][0] * inv); o.y = f2bf(O[m][nt][1] * inv);
            o.z = f2bf(O[m][nt][2] * inv); o.w = f2bf(O[m][nt][3] * inv);
            *(ushort4*)(dst + nt * 16 + quad * 4) = o;
        }
    }
}

// ---------- GEMM2: 16-row blocks, wave = col-quarter (unchanged R10) -------
__global__ __launch_bounds__(256) void gemm2_mfma(
    const u16* __restrict__ ah, const u16* __restrict__ wpth,
    float* __restrict__ out)
{
    const int bm = blockIdx.x * 16;
    const int wv = threadIdx.x >> 6, lane = threadIdx.x & 63;
    const int lr = lane & 15, quad = lane >> 4;
    const int cq = wv;

    const u16* arow  = ah + (size_t)(bm + lr) * ATT_LD + quad * 8;
    const u16* w0row = wpth + (size_t)(cq * 32 + lr) * ATT_LD + quad * 8;
    const u16* w1row = w0row + (size_t)16 * ATT_LD;

    f32x4 acc0 = {0.f, 0.f, 0.f, 0.f}, acc1 = {0.f, 0.f, 0.f, 0.f};
    #pragma unroll 8
    for (int k0 = 0; k0 < ATT_LD; k0 += 32) {
        short8 a  = *(const short8*)(arow + k0);
        short8 w0 = *(const short8*)(w0row + k0);
        short8 w1 = *(const short8*)(w1row + k0);
        acc0 = MFMA16(w0, a, acc0, 0, 0, 0);
        acc1 = MFMA16(w1, a, acc1, 0, 0, 0);
    }
    float* orow = out + (size_t)(bm + lr) * DIM_ + cq * 32;
    *(float4*)(orow + quad * 4)      = *(float4*)&acc0;
    *(float4*)(orow + 16 + quad * 4) = *(float4*)&acc1;
}

// ---------- launch ----------------------------------------------------------
extern "C" void kernel_launch(void* const* d_in, const int* in_sizes, int n_in,
                              void* d_out, int out_size, void* d_ws, size_t ws_size,
                              hipStream_t stream)
{
    const float* x     = (const float*)d_in[0];
    const float* Wqkv  = (const float*)d_in[1];
    const float* Wproj = (const float*)d_in[2];
    float* out = (float*)d_out;

    u16* xh   = (u16*)d_ws;
    u16* wth  = xh   + (size_t)NX;
    u16* wpth = wth  + (size_t)NWQ;
    u16* qkvb = wpth + (size_t)NWP;                         // 8192*3072
    u16* vg   = qkvb + (size_t)8192 * QKV_LD;               // 4*4*128*2048
    u16* ahp  = vg   + (size_t)BATCH_ * KVH_ * DIM_ * SEQ_; // 8192*2048

    prep<<<1024 + 640, 256, 0, stream>>>(x, Wqkv, Wproj, xh, wth, wpth);

    gemm1_mfma<<<dim3(QKV_LD / 64, 8192 / 128), 256, 0, stream>>>(
        xh, wth, qkvb, vg);

    attn_mfma<<<dim3(SEQ_ / 32, KVH_, BATCH_), 256, 0, stream>>>(qkvb, vg, ahp);

    gemm2_mfma<<<8192 / 16, 256, 0, stream>>>(ahp, wpth, out);
}

// Round 12
// 201.215 us; speedup vs baseline: 1.0469x; 1.0469x over previous
//
#include <hip/hip_runtime.h>
#include <math.h>

#define DIM_    128
#define QH_     16
#define KVH_    4
#define WIN_    512
#define BATCH_  4
#define SEQ_    2048
#define QKV_LD  3072
#define ATT_LD  2048

#define NX   (BATCH_*SEQ_*DIM_)   // 1048576
#define NWQ  (DIM_*QKV_LD)        // 393216
#define NWP  (ATT_LD*DIM_)        // 262144

typedef __attribute__((ext_vector_type(8))) short short8;
typedef __attribute__((ext_vector_type(4))) float f32x4;
typedef unsigned short u16;
typedef unsigned int u32;

__device__ __forceinline__ u16 f2bf(float f) {
    u32 u = __float_as_uint(f);
    u += 0x7fff + ((u >> 16) & 1);
    return (u16)(u >> 16);
}
__device__ __forceinline__ float bf2f(u16 u) {
    return __uint_as_float(((u32)u) << 16);
}
#define MFMA16 __builtin_amdgcn_mfma_f32_16x16x32_bf16

#if __has_builtin(__builtin_amdgcn_exp2f)
#define EXP2F __builtin_amdgcn_exp2f
#else
#define EXP2F exp2f
#endif

__device__ __forceinline__ void gload_lds16(const u16* g, u16* l) {
    __builtin_amdgcn_global_load_lds(
        (const __attribute__((address_space(1))) unsigned int*)(const void*)g,
        (__attribute__((address_space(3))) unsigned int*)(void*)l, 16, 0, 0);
}

// ---------- prep: xcvt + wtrans fused (unchanged R11) ----------------------
__global__ __launch_bounds__(256) void prep(
    const float* __restrict__ x, const float* __restrict__ Wqkv,
    const float* __restrict__ Wproj,
    u16* __restrict__ xh, u16* __restrict__ wth, u16* __restrict__ wpth)
{
    if (blockIdx.x < 1024) {
        const size_t t = (size_t)blockIdx.x * 256 + threadIdx.x;
        float4 v = *(const float4*)(x + 4 * t);
        ushort4 o;
        o.x = f2bf(v.x); o.y = f2bf(v.y); o.z = f2bf(v.z); o.w = f2bf(v.w);
        *(ushort4*)(xh + 4 * t) = o;
        return;
    }
    __shared__ float T[32][33];
    int tile = blockIdx.x - 1024;
    const float* src; u16* dst; int K, N;
    if (tile < 384) { src = Wqkv;  dst = wth;  K = 128;  N = 3072; }
    else { tile -= 384; src = Wproj; dst = wpth; K = 2048; N = 128; }
    const int ntile = N >> 5;
    const int k0 = (tile / ntile) << 5, n0 = (tile % ntile) << 5;
    const int tx = threadIdx.x & 31, ty = threadIdx.x >> 5;
    #pragma unroll
    for (int i = 0; i < 4; ++i)
        T[ty + 8 * i][tx] = src[(size_t)(k0 + ty + 8 * i) * N + n0 + tx];
    __syncthreads();
    #pragma unroll
    for (int i = 0; i < 4; ++i)
        dst[(size_t)(n0 + ty + 8 * i) * K + k0 + tx] = f2bf(T[tx][ty + 8 * i]);
}

// ---------- GEMM1 (bf16 MFMA, LDS-tiled): qkv = x @ Wqkv (unchanged) -------
__global__ __launch_bounds__(256) void gemm1_mfma(
    const u16* __restrict__ xh, const u16* __restrict__ wth,
    u16* __restrict__ qkvb, u16* __restrict__ vg)
{
    __shared__ u16 Ab[32][512];
    __shared__ u16 Bb[16][512];
    const int bn = blockIdx.x * 64;
    const int bm = blockIdx.y * 128;
    const int tid = threadIdx.x;
    const int wv = tid >> 6, lane = tid & 63;
    const int lr = lane & 15, quad = lane >> 4;
    const int lo = lane & 15, hi = lane >> 4;

    #pragma unroll
    for (int i = 0; i < 12; ++i) {
        const int idx = wv * 12 + i;
        if (idx < 32) {
            const int mt = idx >> 2, s = idx & 3;
            gload_lds16(xh + (size_t)(bm + mt * 16 + lo) * DIM_ + s * 32 + hi * 8,
                        &Ab[idx][0]);
        } else {
            const int j = idx - 32, nt = j >> 2, s = j & 3;
            gload_lds16(wth + (size_t)(bn + nt * 16 + lo) * DIM_ + s * 32 + hi * 8,
                        &Bb[j][0]);
        }
    }
    __syncthreads();

    const int wr = wv >> 1, wc = wv & 1;
    f32x4 acc[4][2] = {};
    if (bn < 2560) {                       // transposed: ushort4 stores
        #pragma unroll
        for (int s = 0; s < 4; ++s) {
            short8 af[4], bf[2];
            #pragma unroll
            for (int mt = 0; mt < 4; ++mt)
                af[mt] = *(const short8*)&Ab[(wr * 4 + mt) * 4 + s][lane * 8];
            #pragma unroll
            for (int nt = 0; nt < 2; ++nt)
                bf[nt] = *(const short8*)&Bb[(wc * 2 + nt) * 4 + s][lane * 8];
            #pragma unroll
            for (int mt = 0; mt < 4; ++mt)
                #pragma unroll
                for (int nt = 0; nt < 2; ++nt)
                    acc[mt][nt] = MFMA16(bf[nt], af[mt], acc[mt][nt], 0, 0, 0);
        }
        #pragma unroll
        for (int mt = 0; mt < 4; ++mt)
            #pragma unroll
            for (int nt = 0; nt < 2; ++nt) {
                ushort4 o;
                o.x = f2bf(acc[mt][nt][0]); o.y = f2bf(acc[mt][nt][1]);
                o.z = f2bf(acc[mt][nt][2]); o.w = f2bf(acc[mt][nt][3]);
                *(ushort4*)(qkvb
                    + (size_t)(bm + wr * 64 + mt * 16 + lr) * QKV_LD
                    + bn + wc * 32 + nt * 16 + quad * 4) = o;
            }
    } else {                               // V region: normal, seq in regs
        #pragma unroll
        for (int s = 0; s < 4; ++s) {
            short8 af[4], bf[2];
            #pragma unroll
            for (int mt = 0; mt < 4; ++mt)
                af[mt] = *(const short8*)&Ab[(wr * 4 + mt) * 4 + s][lane * 8];
            #pragma unroll
            for (int nt = 0; nt < 2; ++nt)
                bf[nt] = *(const short8*)&Bb[(wc * 2 + nt) * 4 + s][lane * 8];
            #pragma unroll
            for (int mt = 0; mt < 4; ++mt)
                #pragma unroll
                for (int nt = 0; nt < 2; ++nt)
                    acc[mt][nt] = MFMA16(af[mt], bf[nt], acc[mt][nt], 0, 0, 0);
        }
        #pragma unroll
        for (int mt = 0; mt < 4; ++mt)
            #pragma unroll
            for (int nt = 0; nt < 2; ++nt) {
                const int ncol = bn + wc * 32 + nt * 16 + lr - 2560;
                const int kvh = ncol >> 7, d = ncol & 127;
                const int m0 = bm + wr * 64 + mt * 16 + quad * 4;
                ushort4 o;
                o.x = f2bf(acc[mt][nt][0]); o.y = f2bf(acc[mt][nt][1]);
                o.z = f2bf(acc[mt][nt][2]); o.w = f2bf(acc[mt][nt][3]);
                *(ushort4*)(vg + ((size_t)((m0 >> 11) * KVH_ + kvh) * DIM_ + d)
                            * SEQ_ + (m0 & 2047)) = o;
            }
    }
}

// ---------- Attention: EXACT R8/R10 pipeline + XCD-locality swizzle --------
// 1D grid of 1024. Assuming round-robin block->XCD dispatch (id & 7 = XCD):
// pair (b,kvh) = (id&7) + 8*(idx&1)  -> all 64 q-tiles of a pair on ONE XCD.
// K+V per pair = 1MB; 2 pairs/XCD = 2MB < 4MB L2 -> re-fetches become L2 hits.
__global__ __launch_bounds__(256) void attn_mfma(
    const u16* __restrict__ qkvb, const u16* __restrict__ vg,
    u16* __restrict__ ah)
{
    const int xcd  = blockIdx.x & 7;
    const int idx  = blockIdx.x >> 3;          // 0..127 per XCD residue
    const int pair = xcd + 8 * (idx & 1);      // 0..15
    const int qt   = idx >> 1;                 // 0..63
    const int b    = pair >> 2, kvh = pair & 3;
    const int q0 = qt << 5;
    const int tid = threadIdx.x;
    const int wv = tid >> 6, lane = tid & 63;
    const int lr = lane & 15, quad = lane >> 4;
    const int h = kvh * 4 + wv;

    __shared__ u16 Kb[4][8][512];    // 32KB  4-slot ring, sub p = nt*4+s
    __shared__ u16 Vb[4][8][512];    // 32KB
    __shared__ u16 Pt[4][32][36];    // 9KB   per-wave P^T [query][key]

    const float scale2 = 0.08838834764831845f * 1.4426950408889634f;
    const float slope2 = exp2f(-0.5f * (float)(h + 1)) * 1.4426950408889634f;
    const int jbase = max(0, q0 - WIN_);
    const int nch = (q0 + 32 - jbase) >> 5;
    const size_t rowb = (size_t)b * SEQ_;
    const u16* kg  = qkvb + rowb * QKV_LD + (QH_ + kvh) * DIM_;
    const u16* vgb = vg + (size_t)(b * KVH_ + kvh) * DIM_ * SEQ_;
    const int lo = lane & 15, hi = lane >> 4;

    short8 qf[2][4];
    #pragma unroll
    for (int m = 0; m < 2; ++m) {
        const u16* qp = qkvb + (rowb + q0 + m * 16 + lr) * QKV_LD
                        + h * DIM_ + quad * 8;
        #pragma unroll
        for (int s = 0; s < 4; ++s) qf[m][s] = *(const short8*)(qp + 32 * s);
    }

    float alpha[2];
    #pragma unroll
    for (int m = 0; m < 2; ++m) {
        const int q = q0 + m * 16 + lr;
        const int rm = (q < WIN_) ? q : WIN_;
        alpha[m] = slope2 * (float)(q - rm);
    }

    f32x4 O[2][8] = {};              // O^T: regs = d, lane col = query
    float rs[2] = {0.f, 0.f};

    #define STAGE(CH, SLOT) do {                                              \
        const int _jk = jbase + ((CH) << 5);                                  \
        _Pragma("unroll")                                                     \
        for (int _t = 0; _t < 2; ++_t) {                                      \
            const int _p = wv + _t * 4;                                       \
            gload_lds16(kg + (size_t)(_jk + (_p >> 2) * 16 + lo) * QKV_LD     \
                        + (_p & 3) * 32 + hi * 8, &Kb[(SLOT)][_p][0]);        \
            gload_lds16(vgb + (size_t)(_p * 16 + lo) * SEQ_ + _jk + hi * 8,   \
                        &Vb[(SLOT)][_p][0]);                                  \
        }                                                                     \
    } while (0)

    STAGE(0, 0);
    { const int c1 = (1 < nch) ? 1 : (nch - 1); STAGE(c1, 1); }

    for (int ch = 0; ch < nch; ++ch) {
        const int jk = jbase + (ch << 5);
        const int slot = ch & 3;
        { const int cn = (ch + 2 < nch) ? (ch + 2) : (nch - 1);
          STAGE(cn, (ch + 2) & 3); }
        __asm__ volatile("s_waitcnt vmcnt(8)" ::: "memory");
        __asm__ volatile("s_barrier" ::: "memory");

        #pragma unroll
        for (int nt = 0; nt < 2; ++nt) {
            f32x4 c0 = {0.f, 0.f, 0.f, 0.f}, c1 = {0.f, 0.f, 0.f, 0.f};
            #pragma unroll
            for (int s = 0; s < 4; ++s) {
                short8 kf = *(const short8*)&Kb[slot][nt * 4 + s][lane * 8];
                c0 = MFMA16(kf, qf[0][s], c0, 0, 0, 0);
                c1 = MFMA16(kf, qf[1][s], c1, 0, 0, 0);
            }
            const int jknt = jk + nt * 16;
            #pragma unroll
            for (int m = 0; m < 2; ++m) {
                const f32x4 c = m ? c1 : c0;
                const int qm0 = q0 + m * 16;
                const float b0 = fmaf(-slope2, (float)(jknt + quad * 4), alpha[m]);
                float e0, e1, e2, e3;
                if (qm0 >= jknt + 15 && qm0 + 15 <= jknt + WIN_) {   // full
                    e0 = EXP2F(fmaf(c[0], scale2, b0));
                    e1 = EXP2F(fmaf(c[1], scale2, b0 - slope2));
                    e2 = EXP2F(fmaf(c[2], scale2, b0 - 2.f * slope2));
                    e3 = EXP2F(fmaf(c[3], scale2, b0 - 3.f * slope2));
                } else {                                              // edge
                    const int q = qm0 + lr, j0q = jknt + quad * 4;
                    float ee[4];
                    #pragma unroll
                    for (int r = 0; r < 4; ++r) {
                        const int rel = q - (j0q + r);
                        const float t = fmaf(c[r], scale2, b0 - (float)r * slope2);
                        ee[r] = ((unsigned)rel <= (unsigned)WIN_) ? EXP2F(t) : 0.f;
                    }
                    e0 = ee[0]; e1 = ee[1]; e2 = ee[2]; e3 = ee[3];
                }
                rs[m] += (e0 + e1) + (e2 + e3);
                ushort4 o;
                o.x = f2bf(e0); o.y = f2bf(e1); o.z = f2bf(e2); o.w = f2bf(e3);
                *(ushort4*)&Pt[wv][m * 16 + lr][nt * 16 + quad * 4] = o;
            }
        }
        __asm__ volatile("s_waitcnt lgkmcnt(0)" ::: "memory");

        short8 pa0 = *(const short8*)&Pt[wv][lr][quad * 8];
        short8 pa1 = *(const short8*)&Pt[wv][16 + lr][quad * 8];
        #pragma unroll
        for (int nt = 0; nt < 8; ++nt) {
            short8 vf = *(const short8*)&Vb[slot][nt][lane * 8];
            O[0][nt] = MFMA16(vf, pa0, O[0][nt], 0, 0, 0);
            O[1][nt] = MFMA16(vf, pa1, O[1][nt], 0, 0, 0);
        }
    }
    #undef STAGE

    __asm__ volatile("s_waitcnt vmcnt(0)" ::: "memory");

    #pragma unroll
    for (int m = 0; m < 2; ++m) {
        rs[m] += __shfl_xor(rs[m], 16);
        rs[m] += __shfl_xor(rs[m], 32);
    }

    #pragma unroll
    for (int m = 0; m < 2; ++m) {
        const float inv = 1.0f / rs[m];
        u16* dst = ah + (rowb + q0 + m * 16 + lr) * (size_t)ATT_LD + h * DIM_;
        #pragma unroll
        for (int nt = 0; nt < 8; ++nt) {
            ushort4 o;
            o.x = f2bf(O[m][nt][0] * inv); o.y = f2bf(O[m][nt][1] * inv);
            o.z = f2bf(O[m][nt][2] * inv); o.w = f2bf(O[m][nt][3] * inv);
            *(ushort4*)(dst + nt * 16 + quad * 4) = o;
        }
    }
}

// ---------- GEMM2: 16-row blocks, wave = col-quarter (unchanged R10) -------
__global__ __launch_bounds__(256) void gemm2_mfma(
    const u16* __restrict__ ah, const u16* __restrict__ wpth,
    float* __restrict__ out)
{
    const int bm = blockIdx.x * 16;
    const int wv = threadIdx.x >> 6, lane = threadIdx.x & 63;
    const int lr = lane & 15, quad = lane >> 4;
    const int cq = wv;

    const u16* arow  = ah + (size_t)(bm + lr) * ATT_LD + quad * 8;
    const u16* w0row = wpth + (size_t)(cq * 32 + lr) * ATT_LD + quad * 8;
    const u16* w1row = w0row + (size_t)16 * ATT_LD;

    f32x4 acc0 = {0.f, 0.f, 0.f, 0.f}, acc1 = {0.f, 0.f, 0.f, 0.f};
    #pragma unroll 8
    for (int k0 = 0; k0 < ATT_LD; k0 += 32) {
        short8 a  = *(const short8*)(arow + k0);
        short8 w0 = *(const short8*)(w0row + k0);
        short8 w1 = *(const short8*)(w1row + k0);
        acc0 = MFMA16(w0, a, acc0, 0, 0, 0);
        acc1 = MFMA16(w1, a, acc1, 0, 0, 0);
    }
    float* orow = out + (size_t)(bm + lr) * DIM_ + cq * 32;
    *(float4*)(orow + quad * 4)      = *(float4*)&acc0;
    *(float4*)(orow + 16 + quad * 4) = *(float4*)&acc1;
}

// ---------- launch ----------------------------------------------------------
extern "C" void kernel_launch(void* const* d_in, const int* in_sizes, int n_in,
                              void* d_out, int out_size, void* d_ws, size_t ws_size,
                              hipStream_t stream)
{
    const float* x     = (const float*)d_in[0];
    const float* Wqkv  = (const float*)d_in[1];
    const float* Wproj = (const float*)d_in[2];
    float* out = (float*)d_out;

    u16* xh   = (u16*)d_ws;
    u16* wth  = xh   + (size_t)NX;
    u16* wpth = wth  + (size_t)NWQ;
    u16* qkvb = wpth + (size_t)NWP;                         // 8192*3072
    u16* vg   = qkvb + (size_t)8192 * QKV_LD;               // 4*4*128*2048
    u16* ahp  = vg   + (size_t)BATCH_ * KVH_ * DIM_ * SEQ_; // 8192*2048

    prep<<<1024 + 640, 256, 0, stream>>>(x, Wqkv, Wproj, xh, wth, wpth);

    gemm1_mfma<<<dim3(QKV_LD / 64, 8192 / 128), 256, 0, stream>>>(
        xh, wth, qkvb, vg);

    attn_mfma<<<1024, 256, 0, stream>>>(qkvb, vg, ahp);

    gemm2_mfma<<<8192 / 16, 256, 0, stream>>>(ahp, wpth, out);
}